// Round 12
// baseline (83.107 us; speedup 1.0000x reference)
//
#include <hip/hip_runtime.h>

#define NB    8
#define NH    16384
#define NL    2048
#define F_HR  64
#define F_LR  128
#define OUT_COLS 198   // 64 + 3 + 128 + 3

// ---------------------------------------------------------------------------
// Kernel A: coarsened argmin, in-block candidate split, SW-pipelined LDS.
// Ladder: R8 62.5us (LDS-bound, 1 wave-read/cand); R10 70.9us (1 wave/SIMD,
// waits exposed); R11 ~45us (16 waves/CU, but ds_read->use dependency left
// lgkmcnt waits exposed: predicted 26, got 45). This round: register double
// buffer — prefetch next 4 candidates into n[] BEFORE computing on c[], so
// 4 reads are in flight under 192 VALU-cyc of compute per iter.
// Block=512thr (8 waves), 256 points (M=4/lane), wave w scans slice
// [w*256, w*256+256). 512 blocks = 2/CU = 4 waves/SIMD. VALU floor 20.5us.
// Key formula text identical to R3 (proven bit-exact across 7 rounds).
// Tie-break: slot k ascending = index ascending; slices ascending; strict <.
// ---------------------------------------------------------------------------
__global__ __launch_bounds__(512, 4) void knn_kernel(
    const float* __restrict__ pos_hr,   // [NB*NH, 3]
    const float* __restrict__ pos_lr,   // [NB*NL, 3]
    int* __restrict__ out_idx)          // [NB*NH]
{
    __shared__ float4 cand[NL];         // 32 KiB (x, y, z, 0.5*|p|^2)
    __shared__ float  pval[8][256];     //  8 KiB per-wave best value
    __shared__ int    pidx[8][256];     //  8 KiB per-wave best index (batch-local)

    const int b  = blockIdx.x >> 6;     // 64 blocks per batch
    const int p0 = blockIdx.x << 8;     // first global point of this block
    const int w  = threadIdx.x >> 6;    // wave id = candidate slice
    const int l  = threadIdx.x & 63;

    const float* pl = pos_lr + (size_t)b * NL * 3;
    for (int j = threadIdx.x; j < NL; j += 512) {
        float x = pl[j * 3 + 0];
        float y = pl[j * 3 + 1];
        float z = pl[j * 3 + 2];
        cand[j] = make_float4(x, y, z, 0.5f * ((x * x + y * y) + z * z));
    }
    __syncthreads();

    // M=4 points per lane (lane-stride 64 within the block's 256 points)
    float phx[4], phy[4], phz[4];
#pragma unroll
    for (int m = 0; m < 4; ++m) {
        const int pt = p0 + (m << 6) + l;
        phx[m] = pos_hr[pt * 3 + 0];
        phy[m] = pos_hr[pt * 3 + 1];
        phz[m] = pos_hr[pt * 3 + 2];
    }

    float best[4][4];
    int   bi[4][4];
#pragma unroll
    for (int m = 0; m < 4; ++m)
#pragma unroll
        for (int k = 0; k < 4; ++k) { best[m][k] = 3.4e38f; bi[m][k] = k; }

    const int base = w << 8;            // this wave's slice start (batch-local)

    // register double buffer: c = current 4 candidates, n = prefetched next 4
    float4 c[4];
#pragma unroll
    for (int k = 0; k < 4; ++k) c[k] = cand[base + k];

    for (int j = 0; j < 256; j += 4) {
        float4 n[4];
        const int jn = (j + 4) & 255;   // wrap: final prefetch unused but valid
#pragma unroll
        for (int k = 0; k < 4; ++k) n[k] = cand[base + jn + k];

#pragma unroll
        for (int m = 0; m < 4; ++m) {
#pragma unroll
            for (int k = 0; k < 4; ++k) {
                float d = fmaf(-phz[m], c[k].z,
                         fmaf(-phy[m], c[k].y,
                         fmaf(-phx[m], c[k].x, c[k].w)));
                if (d < best[m][k]) { best[m][k] = d; bi[m][k] = j + k; }  // strict <
            }
        }
#pragma unroll
        for (int k = 0; k < 4; ++k) c[k] = n[k];
    }

    // slot merge (ascending k = ascending index; == keeps lower index)
#pragma unroll
    for (int m = 0; m < 4; ++m) {
        float v = best[m][0]; int i = bi[m][0];
#pragma unroll
        for (int k = 1; k < 4; ++k) {
            if (best[m][k] < v || (best[m][k] == v && bi[m][k] < i)) {
                v = best[m][k]; i = bi[m][k];
            }
        }
        const int ptl = (m << 6) + l;   // block-local point
        pval[w][ptl] = v;
        pidx[w][ptl] = base + i;        // batch-local candidate index
    }
    __syncthreads();

    // cross-wave merge: slices ascending, strict < keeps first occurrence
    const int t = threadIdx.x;
    if (t < 256) {
        float v = pval[0][t]; int i = pidx[0][t];
#pragma unroll
        for (int q = 1; q < 8; ++q) {
            const float qv = pval[q][t];
            if (qv < v) { v = qv; i = pidx[q][t]; }
        }
        out_idx[p0 + t] = b * NL + i;
    }
}

// ---------------------------------------------------------------------------
// Kernel B: PHASE-SPLIT assemble (R8, proven 32.4 us timed). DO NOT TOUCH.
// P1: 11 independent idx loads; P2: 11 gathers (counted vmcnt waits keep
// loads pipelined); P3: 11 coalesced stores. Incremental row/col decode.
// ---------------------------------------------------------------------------
#define GRID_B   3072
#define NTHREADS (GRID_B * 256)                 // 786,432
// R0 = 8*16384*198 = 25,952,256 = 33 * NTHREADS exactly -> no bounds checks
#define ROW_STEP 3971                           // 786432 / 198
#define COL_STEP 174                            // 786432 % 198
#define BATCH    11                             // 33 = 3 * 11

__global__ __launch_bounds__(256) void assemble_kernel(
    const float* __restrict__ x_hr,     // [NB*NH, 64]
    const float* __restrict__ pos_hr,   // [NB*NH, 3]
    const float* __restrict__ x_lr,     // [NB*NL, 128]
    const float* __restrict__ pos_lr,   // [NB*NL, 3]
    const int* __restrict__ idx,        // [NB*NH]
    float* __restrict__ out)
{
    const int R0 = NB * NH * OUT_COLS;        // 25,952,256
    const int Z  = NB * NH * 3;               // 393,216 zeros after R0
    const int TAIL = Z + NB * NH;             // 524,288 total tail elems

    const int tid = blockIdx.x * blockDim.x + threadIdx.x;

    int row = tid / OUT_COLS;                 // one division per thread
    int col = tid - row * OUT_COLS;

    for (int b = 0; b < 3; ++b) {
        int   rs[BATCH], cs[BATCH], ls[BATCH];
        float vs[BATCH];

#pragma unroll
        for (int k = 0; k < BATCH; ++k) {
            rs[k] = row;
            cs[k] = col;
            ls[k] = idx[row];
            col += COL_STEP;
            const int carry = (col >= OUT_COLS) ? 1 : 0;
            col -= carry ? OUT_COLS : 0;
            row += ROW_STEP + carry;
        }

#pragma unroll
        for (int k = 0; k < BATCH; ++k) {
            const int c = cs[k];
            const float* a =
                  c < F_HR            ? x_hr   + rs[k] * F_HR + c
                : c < F_HR + 3        ? pos_hr + rs[k] * 3    + (c - F_HR)
                : c < F_HR + 3 + F_LR ? x_lr   + ls[k] * F_LR + (c - (F_HR + 3))
                :                       pos_lr + ls[k] * 3    + (c - (F_HR + 3 + F_LR));
            vs[k] = *a;
        }

#pragma unroll
        for (int k = 0; k < BATCH; ++k) {
            out[tid + (b * BATCH + k) * NTHREADS] = vs[k];
        }
    }

    if (tid < TAIL) {
        const float v = tid < Z ? 0.0f : (float)((tid - Z) >> 14);  // NH = 2^14
        out[R0 + tid] = v;
    }
}

extern "C" void kernel_launch(void* const* d_in, const int* in_sizes, int n_in,
                              void* d_out, int out_size, void* d_ws, size_t ws_size,
                              hipStream_t stream) {
    const float* x_hr   = (const float*)d_in[0];
    const float* pos_hr = (const float*)d_in[1];
    // d_in[2] = batch_hr (int32) — unused, batch is contiguous repeats
    const float* x_lr   = (const float*)d_in[3];
    const float* pos_lr = (const float*)d_in[4];
    // d_in[5] = batch_lr (int32) — unused

    int* idx = (int*)d_ws;                    // NB*NH ints = 512 KiB scratch

    knn_kernel<<<dim3(NB * NH / 256), dim3(512), 0, stream>>>(pos_hr, pos_lr, idx);
    assemble_kernel<<<dim3(GRID_B), dim3(256), 0, stream>>>(
        x_hr, pos_hr, x_lr, pos_lr, idx, (float*)d_out);
}

// Round 13
// 75.864 us; speedup vs baseline: 1.0955x; 1.0955x over previous
//
#include <hip/hip_runtime.h>

#define NB    8
#define NH    16384
#define NL    2048
#define F_HR  64
#define F_LR  128
#define OUT_COLS 198   // 64 + 3 + 128 + 3

// ---------------------------------------------------------------------------
// Kernel A: argmin, M=8 coarsening, 16-way in-block candidate slicing.
// Ladder: R8 62.5us (M=1, LDS-bound 9.2cyc/bcast-read); R10 refuted 1 wave/
// SIMD; R11 45us (M=4, 8 slices, 4 waves/SIMD); R12 refuted reg double-buffer
// (copy movs +5.6us). Here: M=8 halves LDS reads/CU (4096->2048, ~7.9us) and
// gives 96 VALU instrs per 2 ds_reads (self-hiding), at 4 waves/SIMD.
// Block = 1024thr = 16 waves; all waves cover the same 512 points; wave w
// scans candidate slice [w*128, w*128+128). 256 blocks = 1/CU.
// Key formula text identical to R3 (bit-exact vs numpy across 8 rounds).
// Order: slot k ascending, slice w ascending, strict < => first occurrence.
// ---------------------------------------------------------------------------
__global__ __launch_bounds__(1024, 4) void knn_kernel(
    const float* __restrict__ pos_hr,   // [NB*NH, 3]
    const float* __restrict__ pos_lr,   // [NB*NL, 3]
    int* __restrict__ out_idx)          // [NB*NH]
{
    __shared__ float4 cand[NL];         // 32 KiB (x, y, z, 0.5*|p|^2)
    __shared__ float  pval[16][512];    // 32 KiB per-slice best value
    __shared__ int    pidx[16][512];    // 32 KiB per-slice best index (batch-local)

    const int b  = blockIdx.x >> 5;     // 32 blocks per batch
    const int p0 = blockIdx.x << 9;     // first global point (512 per block)
    const int w  = threadIdx.x >> 6;    // wave id = candidate slice [0,16)
    const int l  = threadIdx.x & 63;

    // stage candidates (formula text = proven R3 kernel)
    const float* pl = pos_lr + (size_t)b * NL * 3;
    for (int j = threadIdx.x; j < NL; j += 1024) {
        float x = pl[j * 3 + 0];
        float y = pl[j * 3 + 1];
        float z = pl[j * 3 + 2];
        cand[j] = make_float4(x, y, z, 0.5f * ((x * x + y * y) + z * z));
    }
    __syncthreads();

    // M=8 points per lane (lane-stride 64 within the block's 512 points)
    float phx[8], phy[8], phz[8];
#pragma unroll
    for (int m = 0; m < 8; ++m) {
        const int pt = p0 + (m << 6) + l;
        phx[m] = pos_hr[pt * 3 + 0];
        phy[m] = pos_hr[pt * 3 + 1];
        phz[m] = pos_hr[pt * 3 + 2];
    }

    const int base = w << 7;            // slice start (batch-local)

    float best[8][2];
    int   bi[8][2];
#pragma unroll
    for (int m = 0; m < 8; ++m) {
        best[m][0] = 3.4e38f; best[m][1] = 3.4e38f;
        bi[m][0] = base;      bi[m][1] = base + 1;
    }

    for (int j = 0; j < 128; j += 2) {
        const float4 c0 = cand[base + j];
        const float4 c1 = cand[base + j + 1];
#pragma unroll
        for (int m = 0; m < 8; ++m) {
            float d0 = fmaf(-phz[m], c0.z, fmaf(-phy[m], c0.y, fmaf(-phx[m], c0.x, c0.w)));
            float d1 = fmaf(-phz[m], c1.z, fmaf(-phy[m], c1.y, fmaf(-phx[m], c1.x, c1.w)));
            if (d0 < best[m][0]) { best[m][0] = d0; bi[m][0] = base + j; }     // strict <
            if (d1 < best[m][1]) { best[m][1] = d1; bi[m][1] = base + j + 1; }
        }
    }

    // slot merge (k ascending = index ascending; == keeps lower index)
#pragma unroll
    for (int m = 0; m < 8; ++m) {
        float v = best[m][0]; int i = bi[m][0];
        if (best[m][1] < v || (best[m][1] == v && bi[m][1] < i)) {
            v = best[m][1]; i = bi[m][1];
        }
        const int ptl = (m << 6) + l;   // block-local point
        pval[w][ptl] = v;
        pidx[w][ptl] = i;               // batch-local candidate index
    }
    __syncthreads();

    // cross-slice merge: slices ascending, strict < keeps first occurrence
    const int t = threadIdx.x;
    if (t < 512) {
        float v = pval[0][t]; int i = pidx[0][t];
#pragma unroll
        for (int q = 1; q < 16; ++q) {
            const float qv = pval[q][t];
            if (qv < v) { v = qv; i = pidx[q][t]; }
        }
        out_idx[p0 + t] = b * NL + i;
    }
}

// ---------------------------------------------------------------------------
// Kernel B: PHASE-SPLIT assemble (R8, proven 32.4 us timed). DO NOT TOUCH.
// P1: 11 independent idx loads; P2: 11 gathers (counted vmcnt waits keep
// loads pipelined); P3: 11 coalesced stores. Incremental row/col decode.
// ---------------------------------------------------------------------------
#define GRID_B   3072
#define NTHREADS (GRID_B * 256)                 // 786,432
// R0 = 8*16384*198 = 25,952,256 = 33 * NTHREADS exactly -> no bounds checks
#define ROW_STEP 3971                           // 786432 / 198
#define COL_STEP 174                            // 786432 % 198
#define BATCH    11                             // 33 = 3 * 11

__global__ __launch_bounds__(256) void assemble_kernel(
    const float* __restrict__ x_hr,     // [NB*NH, 64]
    const float* __restrict__ pos_hr,   // [NB*NH, 3]
    const float* __restrict__ x_lr,     // [NB*NL, 128]
    const float* __restrict__ pos_lr,   // [NB*NL, 3]
    const int* __restrict__ idx,        // [NB*NH]
    float* __restrict__ out)
{
    const int R0 = NB * NH * OUT_COLS;        // 25,952,256
    const int Z  = NB * NH * 3;               // 393,216 zeros after R0
    const int TAIL = Z + NB * NH;             // 524,288 total tail elems

    const int tid = blockIdx.x * blockDim.x + threadIdx.x;

    int row = tid / OUT_COLS;                 // one division per thread
    int col = tid - row * OUT_COLS;

    for (int b = 0; b < 3; ++b) {
        int   rs[BATCH], cs[BATCH], ls[BATCH];
        float vs[BATCH];

#pragma unroll
        for (int k = 0; k < BATCH; ++k) {
            rs[k] = row;
            cs[k] = col;
            ls[k] = idx[row];
            col += COL_STEP;
            const int carry = (col >= OUT_COLS) ? 1 : 0;
            col -= carry ? OUT_COLS : 0;
            row += ROW_STEP + carry;
        }

#pragma unroll
        for (int k = 0; k < BATCH; ++k) {
            const int c = cs[k];
            const float* a =
                  c < F_HR            ? x_hr   + rs[k] * F_HR + c
                : c < F_HR + 3        ? pos_hr + rs[k] * 3    + (c - F_HR)
                : c < F_HR + 3 + F_LR ? x_lr   + ls[k] * F_LR + (c - (F_HR + 3))
                :                       pos_lr + ls[k] * 3    + (c - (F_HR + 3 + F_LR));
            vs[k] = *a;
        }

#pragma unroll
        for (int k = 0; k < BATCH; ++k) {
            out[tid + (b * BATCH + k) * NTHREADS] = vs[k];
        }
    }

    if (tid < TAIL) {
        const float v = tid < Z ? 0.0f : (float)((tid - Z) >> 14);  // NH = 2^14
        out[R0 + tid] = v;
    }
}

extern "C" void kernel_launch(void* const* d_in, const int* in_sizes, int n_in,
                              void* d_out, int out_size, void* d_ws, size_t ws_size,
                              hipStream_t stream) {
    const float* x_hr   = (const float*)d_in[0];
    const float* pos_hr = (const float*)d_in[1];
    // d_in[2] = batch_hr (int32) — unused, batch is contiguous repeats
    const float* x_lr   = (const float*)d_in[3];
    const float* pos_lr = (const float*)d_in[4];
    // d_in[5] = batch_lr (int32) — unused

    int* idx = (int*)d_ws;                    // NB*NH ints = 512 KiB scratch

    knn_kernel<<<dim3(256), dim3(1024), 0, stream>>>(pos_hr, pos_lr, idx);
    assemble_kernel<<<dim3(GRID_B), dim3(256), 0, stream>>>(
        x_hr, pos_hr, x_lr, pos_lr, idx, (float*)d_out);
}

// Round 14
// 70.316 us; speedup vs baseline: 1.1819x; 1.0789x over previous
//
#include <hip/hip_runtime.h>

#define NB    8
#define NH    16384
#define NL    2048
#define F_HR  64
#define F_LR  128
#define OUT_COLS 198   // 64 + 3 + 128 + 3

// ---------------------------------------------------------------------------
// Mixed-role kernel 1: blocks [0,512) = knn (R11 design, proven 45us);
// blocks [512,768) = idx-independent output copy (cols 0..66 + zeros+batch).
// Rationale (R13 post-mortem): knn is VALU-wall-bound (~43-45us) using ~0
// HBM; the copy is pure-memory. Co-residency: 48KB LDS x2 knn + 1 copy block
// (also reserves 48KB) = 144KB <= 160KB, 24 waves <= 32, so every CU overlaps
// copy traffic under knn compute in either dispatch order.
// knn: key = 0.5*|pl|^2 - <ph,pl> (3-FMA text identical to R3; argmins match
// numpy bit-exactly across 9 passing rounds). M=4 points/lane, 8 candidate
// slices, slot/slice ascending + strict '<' = first-occurrence.
// ---------------------------------------------------------------------------
__global__ __launch_bounds__(512, 4) void mixed_kernel(
    const float* __restrict__ pos_hr,   // [NB*NH, 3]
    const float* __restrict__ pos_lr,   // [NB*NL, 3]
    const float* __restrict__ x_hr,     // [NB*NH, 64]
    int* __restrict__ out_idx,          // [NB*NH]
    float* __restrict__ out)
{
    __shared__ float4 cand[NL];         // 32 KiB (x, y, z, 0.5*|p|^2)
    __shared__ float  pval[8][256];     //  8 KiB per-slice best value
    __shared__ int    pidx[8][256];     //  8 KiB per-slice best index

    if (blockIdx.x < 512) {
        // ----------------------------- knn role -----------------------------
        const int b  = blockIdx.x >> 6;     // 64 blocks per batch
        const int p0 = blockIdx.x << 8;     // first global point of this block
        const int w  = threadIdx.x >> 6;    // wave id = candidate slice
        const int l  = threadIdx.x & 63;

        const float* pl = pos_lr + (size_t)b * NL * 3;
        for (int j = threadIdx.x; j < NL; j += 512) {
            float x = pl[j * 3 + 0];
            float y = pl[j * 3 + 1];
            float z = pl[j * 3 + 2];
            cand[j] = make_float4(x, y, z, 0.5f * ((x * x + y * y) + z * z));
        }
        __syncthreads();

        float phx[4], phy[4], phz[4];
#pragma unroll
        for (int m = 0; m < 4; ++m) {
            const int pt = p0 + (m << 6) + l;
            phx[m] = pos_hr[pt * 3 + 0];
            phy[m] = pos_hr[pt * 3 + 1];
            phz[m] = pos_hr[pt * 3 + 2];
        }

        float best[4][2];
        int   bi[4][2];
#pragma unroll
        for (int m = 0; m < 4; ++m) {
            best[m][0] = 3.4e38f; best[m][1] = 3.4e38f;
            bi[m][0] = 0;         bi[m][1] = 1;
        }

        const int base = w << 8;            // slice start (batch-local)
        for (int j = 0; j < 256; j += 2) {
            const float4 c0 = cand[base + j];
            const float4 c1 = cand[base + j + 1];
#pragma unroll
            for (int m = 0; m < 4; ++m) {
                float d0 = fmaf(-phz[m], c0.z, fmaf(-phy[m], c0.y, fmaf(-phx[m], c0.x, c0.w)));
                float d1 = fmaf(-phz[m], c1.z, fmaf(-phy[m], c1.y, fmaf(-phx[m], c1.x, c1.w)));
                if (d0 < best[m][0]) { best[m][0] = d0; bi[m][0] = j; }     // strict <
                if (d1 < best[m][1]) { best[m][1] = d1; bi[m][1] = j + 1; }
            }
        }

#pragma unroll
        for (int m = 0; m < 4; ++m) {
            float v = best[m][0]; int i = bi[m][0];
            if (best[m][1] < v || (best[m][1] == v && bi[m][1] < i)) {
                v = best[m][1]; i = bi[m][1];
            }
            const int ptl = (m << 6) + l;
            pval[w][ptl] = v;
            pidx[w][ptl] = base + i;
        }
        __syncthreads();

        const int t = threadIdx.x;
        if (t < 256) {
            float v = pval[0][t]; int i = pidx[0][t];
#pragma unroll
            for (int q = 1; q < 8; ++q) {
                const float qv = pval[q][t];
                if (qv < v) { v = qv; i = pidx[q][t]; }
            }
            out_idx[p0 + t] = b * NL + i;
        }
    } else {
        // ----------------------------- copy role ----------------------------
        // cols 0..66 of 512 rows + this block's share of zeros/batch regions.
        const int cb = blockIdx.x - 512;    // [0,256)
        const int r0 = cb << 9;             // 512 rows per block

        // 512 rows x 67 cols = 34304 elems; single-level loads, no chains
#pragma unroll 4
        for (int e = threadIdx.x; e < 512 * 67; e += 512) {
            const int rl  = e / 67;          // compiler magic-div
            const int c   = e - rl * 67;
            const int row = r0 + rl;
            const float v = (c < F_HR) ? x_hr[(row << 6) + c]
                                       : pos_hr[row * 3 + (c - F_HR)];
            out[row * OUT_COLS + c] = v;
        }

        // zeros [R0, R0+Z) and batch [R0+Z, R0+Z+NB*NH): 2048 elems per block
        const int R0 = NB * NH * OUT_COLS;  // 25,952,256
        const int Z  = NB * NH * 3;         // 393,216
        const int z0 = cb << 11;
#pragma unroll
        for (int e = threadIdx.x; e < 2048; e += 512) {
            const int i = z0 + e;
            out[R0 + i] = (i < Z) ? 0.0f : (float)((i - Z) >> 14);  // NH = 2^14
        }
    }
}

// ---------------------------------------------------------------------------
// Kernel 2: slim assemble — idx-dependent cols 67..197 only (131 per row).
// R8's proven phase-split structure (P1 idx loads / P2 gathers / P3 stores);
// 22 iterations, only the last one guarded. Incremental row/col decode.
// ---------------------------------------------------------------------------
#define GRID_B   3072
#define NTHREADS (GRID_B * 256)                 // 786,432
#define GCOLS    131
#define TOTAL_G  (NB * NH * GCOLS)              // 17,170,432
#define GROW_STEP 6003                          // 786432 / 131
#define GCOL_STEP 39                            // 786432 % 131
#define BATCH    11                             // 22 iters = 2 * 11

__global__ __launch_bounds__(256) void assemble_kernel(
    const float* __restrict__ x_lr,     // [NB*NL, 128]
    const float* __restrict__ pos_lr,   // [NB*NL, 3]
    const int* __restrict__ idx,        // [NB*NH]
    float* __restrict__ out)
{
    const int tid = blockIdx.x * blockDim.x + threadIdx.x;

    int row = tid / GCOLS;
    int col = tid - row * GCOLS;

    for (int b = 0; b < 2; ++b) {
        int   rs[BATCH], cs[BATCH], ls[BATCH];
        float vs[BATCH];

        // P1: independent idx loads (row clamped: final iter can run past end)
#pragma unroll
        for (int k = 0; k < BATCH; ++k) {
            const int rc = row < NB * NH ? row : NB * NH - 1;
            rs[k] = row;
            cs[k] = col;
            ls[k] = idx[rc];
            col += GCOL_STEP;
            const int carry = (col >= GCOLS) ? 1 : 0;
            col -= carry ? GCOLS : 0;
            row += GROW_STEP + carry;
        }

        // P2: gathers — counted vmcnt waits keep loads pipelined
#pragma unroll
        for (int k = 0; k < BATCH; ++k) {
            const int c = cs[k];
            const float* a = (c < F_LR) ? x_lr   + ls[k] * F_LR + c
                                        : pos_lr + ls[k] * 3    + (c - F_LR);
            vs[k] = *a;
        }

        // P3: stores (only the very last iteration can be out of range)
#pragma unroll
        for (int k = 0; k < BATCH; ++k) {
            const int i = tid + (b * BATCH + k) * NTHREADS;
            if (b == 1 && k == BATCH - 1) {
                if (i < TOTAL_G) out[rs[k] * OUT_COLS + 67 + cs[k]] = vs[k];
            } else {
                out[rs[k] * OUT_COLS + 67 + cs[k]] = vs[k];
            }
        }
    }
}

extern "C" void kernel_launch(void* const* d_in, const int* in_sizes, int n_in,
                              void* d_out, int out_size, void* d_ws, size_t ws_size,
                              hipStream_t stream) {
    const float* x_hr   = (const float*)d_in[0];
    const float* pos_hr = (const float*)d_in[1];
    // d_in[2] = batch_hr (int32) — unused, batch is contiguous repeats
    const float* x_lr   = (const float*)d_in[3];
    const float* pos_lr = (const float*)d_in[4];
    // d_in[5] = batch_lr (int32) — unused

    int* idx = (int*)d_ws;                    // NB*NH ints = 512 KiB scratch

    mixed_kernel<<<dim3(768), dim3(512), 0, stream>>>(
        pos_hr, pos_lr, x_hr, idx, (float*)d_out);
    assemble_kernel<<<dim3(GRID_B), dim3(256), 0, stream>>>(
        x_lr, pos_lr, idx, (float*)d_out);
}